// Round 5
// baseline (244.721 us; speedup 1.0000x reference)
//
#include <hip/hip_runtime.h>
#include <hip/hip_cooperative_groups.h>

// Reprojection multi-rig model.
// out[i] = intrs[cam]*(p_cam.xy/p_cam.z) + pps[cam] - points_2d[i]
// where p_cam = R(q)*points_3d[pi] + t,
//       q = rel_q (x) ref_q,  t = rel_t + R(rel_q)*ref_t
// Quaternions stored [x,y,z,w]; rotation p + 2*(w*(v x p) + v x (v x p)).
//
// R5: R4 proved the 32B-aligned pose repack is worth -2.7us on the main
// kernel (45.1 -> 42.4, FETCH/VALU matched prediction), but the extra
// repack DISPATCH costs ~6us of graph-node gap (R1/R3/R4 all show ~5-6us
// per added dispatch boundary). Fix: ONE cooperative kernel, phase 1 =
// grid-stride repack (320 KB, L2-warm), grid.sync(), phase 2 = grid-stride
// main loop (balanced, no tail - avoids R2's blocked-per-thread pitfall).
// NOT repacking points_3d: 8 MB table would recreate R3's L2 thrash.

namespace cg = cooperative_groups;

typedef float f4 __attribute__((ext_vector_type(4)));

enum { NGRP = 10000 };  // fixed by problem spec

// ---------------------------------------------------------- fused kernel ---
__global__ __launch_bounds__(256) void fused_kernel(
    const float2* __restrict__ points_2d,
    const int*    __restrict__ camera_indices,
    const int2*   __restrict__ grouping_indices,
    const int*    __restrict__ point_indices,
    const float*  __restrict__ camera_pps,
    const float*  __restrict__ intrs,
    const float*  __restrict__ points_3d,
    const float*  __restrict__ ref_poses,
    const float*  __restrict__ rel_poses,
    f4*           __restrict__ ws,      // 32B-aligned ref pose records
    float2*       __restrict__ out,
    int n)
{
    __shared__ float s_rel[56];   // 8 rel poses x 7
    __shared__ float s_pps[16];   // 8 cams x 2
    __shared__ float s_intr[16];  // 8 cams x 2
    int tid = threadIdx.x;
    if (tid < 56) s_rel[tid] = rel_poses[tid];
    if (tid < 16) { s_pps[tid] = camera_pps[tid]; s_intr[tid] = intrs[tid]; }
    __syncthreads();

    int gsize = gridDim.x * blockDim.x;
    int gtid  = blockIdx.x * blockDim.x + tid;

    // ---- Phase 1: repack ref poses to 32B-aligned records ----
    // ws[2g+0] = { tx, ty, tz, qx }, ws[2g+1] = { qy, qz, qw, 0 }
    for (int g = gtid; g < NGRP; g += gsize) {
        const float* rp = ref_poses + 7 * g;
        f4 a; a.x = rp[0]; a.y = rp[1]; a.z = rp[2]; a.w = rp[3];
        f4 b; b.x = rp[4]; b.y = rp[5]; b.z = rp[6]; b.w = 0.0f;
        ws[2 * g]     = a;
        ws[2 * g + 1] = b;
    }

    __threadfence();           // device-scope release (cross-XCD visibility)
    cg::this_grid().sync();    // all repack writes visible to all blocks

    // ---- Phase 2: main projection loop (grid-stride, balanced) ----
    for (int i = gtid; i < n; i += gsize) {
        // Coalesced streaming loads (same as R0/R4 champion)
        int2  gm  = grouping_indices[i];
        int   pi  = point_indices[i];
        int   cam = camera_indices[i];
        float2 p2d = points_2d[i];

        // ref pose gather: one 64B line always (32B-aligned record), L2-warm
        f4 ca = ws[2 * gm.x];      // [tx,ty,tz,qx]
        f4 cb = ws[2 * gm.x + 1];  // [qy,qz,qw,0] — same line
        float rtx = ca.x, rty = ca.y, rtz = ca.z;
        float rqx = ca.w, rqy = cb.x, rqz = cb.y, rqw = cb.z;

        // rel pose from LDS
        const float* lp = s_rel + 7 * gm.y;
        float ltx = lp[0], lty = lp[1], ltz = lp[2];
        float lqx = lp[3], lqy = lp[4], lqz = lp[5], lqw = lp[6];

        // t = rel_t + quat_rotate(rel_q, ref_t)
        float uvx = lqy * rtz - lqz * rty;
        float uvy = lqz * rtx - lqx * rtz;
        float uvz = lqx * rty - lqy * rtx;
        float uuvx = lqy * uvz - lqz * uvy;
        float uuvy = lqz * uvx - lqx * uvz;
        float uuvz = lqx * uvy - lqy * uvx;
        float tx = ltx + rtx + 2.0f * (lqw * uvx + uuvx);
        float ty = lty + rty + 2.0f * (lqw * uvy + uuvy);
        float tz = ltz + rtz + 2.0f * (lqw * uvz + uuvz);

        // q = quat_mul(rel_q, ref_q)
        float qw = lqw * rqw - (lqx * rqx + lqy * rqy + lqz * rqz);
        float qx = lqw * rqx + rqw * lqx + (lqy * rqz - lqz * rqy);
        float qy = lqw * rqy + rqw * lqy + (lqz * rqx - lqx * rqz);
        float qz = lqw * rqz + rqw * lqz + (lqx * rqy - lqy * rqx);

        // 3D point gather (6 MB table, L2-partial)
        const float* pp = points_3d + 3 * pi;
        float px = pp[0], py = pp[1], pz = pp[2];

        // p_cam = quat_rotate(q, p) + t
        float v2x = qy * pz - qz * py;
        float v2y = qz * px - qx * pz;
        float v2z = qx * py - qy * px;
        float w2x = qy * v2z - qz * v2y;
        float w2y = qz * v2x - qx * v2z;
        float w2z = qx * v2y - qy * v2x;
        float pcx = px + 2.0f * (qw * v2x + w2x) + tx;
        float pcy = py + 2.0f * (qw * v2y + w2y) + ty;
        float pcz = pz + 2.0f * (qw * v2z + w2z) + tz;

        float invz = 1.0f / pcz;  // IEEE divide for numpy-matching accuracy
        float ux = s_intr[2 * cam]     * (pcx * invz) + s_pps[2 * cam];
        float uy = s_intr[2 * cam + 1] * (pcy * invz) + s_pps[2 * cam + 1];

        out[i] = make_float2(ux - p2d.x, uy - p2d.y);
    }
}

// ------------------------------------- fallback: two-dispatch (R4 path) ---
__global__ __launch_bounds__(256) void repack_ref_kernel(
    const float* __restrict__ ref_poses,
    f4* __restrict__ ws)
{
    int g = blockIdx.x * blockDim.x + threadIdx.x;
    if (g >= NGRP) return;
    const float* rp = ref_poses + 7 * g;
    f4 a; a.x = rp[0]; a.y = rp[1]; a.z = rp[2]; a.w = rp[3];
    f4 b; b.x = rp[4]; b.y = rp[5]; b.z = rp[6]; b.w = 0.0f;
    ws[2 * g]     = a;
    ws[2 * g + 1] = b;
}

__global__ __launch_bounds__(256) void reproj_kernel(
    const float2* __restrict__ points_2d,
    const int*    __restrict__ camera_indices,
    const int2*   __restrict__ grouping_indices,
    const int*    __restrict__ point_indices,
    const float*  __restrict__ camera_pps,
    const float*  __restrict__ intrs,
    const float*  __restrict__ points_3d,
    const f4*     __restrict__ refpk,
    const float*  __restrict__ rel_poses,
    float2*       __restrict__ out,
    int n)
{
    __shared__ float s_rel[56];
    __shared__ float s_pps[16];
    __shared__ float s_intr[16];
    int tid = threadIdx.x;
    if (tid < 56) s_rel[tid] = rel_poses[tid];
    if (tid < 16) { s_pps[tid] = camera_pps[tid]; s_intr[tid] = intrs[tid]; }
    __syncthreads();

    int i = blockIdx.x * blockDim.x + tid;
    if (i >= n) return;

    int2  gm  = grouping_indices[i];
    int   pi  = point_indices[i];
    int   cam = camera_indices[i];
    float2 p2d = points_2d[i];

    f4 ca = refpk[2 * gm.x];
    f4 cb = refpk[2 * gm.x + 1];
    float rtx = ca.x, rty = ca.y, rtz = ca.z;
    float rqx = ca.w, rqy = cb.x, rqz = cb.y, rqw = cb.z;

    const float* lp = s_rel + 7 * gm.y;
    float ltx = lp[0], lty = lp[1], ltz = lp[2];
    float lqx = lp[3], lqy = lp[4], lqz = lp[5], lqw = lp[6];

    float uvx = lqy * rtz - lqz * rty;
    float uvy = lqz * rtx - lqx * rtz;
    float uvz = lqx * rty - lqy * rtx;
    float uuvx = lqy * uvz - lqz * uvy;
    float uuvy = lqz * uvx - lqx * uvz;
    float uuvz = lqx * uvy - lqy * uvx;
    float tx = ltx + rtx + 2.0f * (lqw * uvx + uuvx);
    float ty = lty + rty + 2.0f * (lqw * uvy + uuvy);
    float tz = ltz + rtz + 2.0f * (lqw * uvz + uuvz);

    float qw = lqw * rqw - (lqx * rqx + lqy * rqy + lqz * rqz);
    float qx = lqw * rqx + rqw * lqx + (lqy * rqz - lqz * rqy);
    float qy = lqw * rqy + rqw * lqy + (lqz * rqx - lqx * rqz);
    float qz = lqw * rqz + rqw * lqz + (lqx * rqy - lqy * rqx);

    const float* pp = points_3d + 3 * pi;
    float px = pp[0], py = pp[1], pz = pp[2];

    float v2x = qy * pz - qz * py;
    float v2y = qz * px - qx * pz;
    float v2z = qx * py - qy * px;
    float w2x = qy * v2z - qz * v2y;
    float w2y = qz * v2x - qx * v2z;
    float w2z = qx * v2y - qy * v2x;
    float pcx = px + 2.0f * (qw * v2x + w2x) + tx;
    float pcy = py + 2.0f * (qw * v2y + w2y) + ty;
    float pcz = pz + 2.0f * (qw * v2z + w2z) + tz;

    float invz = 1.0f / pcz;
    float ux = s_intr[2 * cam]     * (pcx * invz) + s_pps[2 * cam];
    float uy = s_intr[2 * cam + 1] * (pcy * invz) + s_pps[2 * cam + 1];

    out[i] = make_float2(ux - p2d.x, uy - p2d.y);
}

// -------------------------------------------------- fallback (no ws) -------
__global__ __launch_bounds__(256) void reproj_inline_kernel(
    const float2* __restrict__ points_2d,
    const int*    __restrict__ camera_indices,
    const int2*   __restrict__ grouping_indices,
    const int*    __restrict__ point_indices,
    const float*  __restrict__ camera_pps,
    const float*  __restrict__ intrs,
    const float*  __restrict__ points_3d,
    const float*  __restrict__ ref_poses,
    const float*  __restrict__ rel_poses,
    float2*       __restrict__ out,
    int n)
{
    __shared__ float s_rel[56];
    __shared__ float s_pps[16];
    __shared__ float s_intr[16];
    int tid = threadIdx.x;
    if (tid < 56) s_rel[tid] = rel_poses[tid];
    if (tid < 16) { s_pps[tid] = camera_pps[tid]; s_intr[tid] = intrs[tid]; }
    __syncthreads();

    int i = blockIdx.x * blockDim.x + tid;
    if (i >= n) return;

    int2  gm  = grouping_indices[i];
    int   pi  = point_indices[i];
    int   cam = camera_indices[i];
    float2 p2d = points_2d[i];

    const float* rp = ref_poses + 7 * gm.x;
    float rtx = rp[0], rty = rp[1], rtz = rp[2];
    float rqx = rp[3], rqy = rp[4], rqz = rp[5], rqw = rp[6];
    const float* lp = s_rel + 7 * gm.y;
    float ltx = lp[0], lty = lp[1], ltz = lp[2];
    float lqx = lp[3], lqy = lp[4], lqz = lp[5], lqw = lp[6];

    float uvx = lqy * rtz - lqz * rty;
    float uvy = lqz * rtx - lqx * rtz;
    float uvz = lqx * rty - lqy * rtx;
    float uuvx = lqy * uvz - lqz * uvy;
    float uuvy = lqz * uvx - lqx * uvz;
    float uuvz = lqx * uvy - lqy * uvx;
    float tx = ltx + rtx + 2.0f * (lqw * uvx + uuvx);
    float ty = lty + rty + 2.0f * (lqw * uvy + uuvy);
    float tz = ltz + rtz + 2.0f * (lqw * uvz + uuvz);

    float qw = lqw * rqw - (lqx * rqx + lqy * rqy + lqz * rqz);
    float qx = lqw * rqx + rqw * lqx + (lqy * rqz - lqz * rqy);
    float qy = lqw * rqy + rqw * lqy + (lqz * rqx - lqx * rqz);
    float qz = lqw * rqz + rqw * lqz + (lqx * rqy - lqy * rqx);

    const float* pp = points_3d + 3 * pi;
    float px = pp[0], py = pp[1], pz = pp[2];

    float v2x = qy * pz - qz * py;
    float v2y = qz * px - qx * pz;
    float v2z = qx * py - qy * px;
    float w2x = qy * v2z - qz * v2y;
    float w2y = qz * v2x - qx * v2z;
    float w2z = qx * v2y - qy * v2x;
    float pcx = px + 2.0f * (qw * v2x + w2x) + tx;
    float pcy = py + 2.0f * (qw * v2y + w2y) + ty;
    float pcz = pz + 2.0f * (qw * v2z + w2z) + tz;

    float invz = 1.0f / pcz;
    float ux = s_intr[2 * cam]     * (pcx * invz) + s_pps[2 * cam];
    float uy = s_intr[2 * cam + 1] * (pcy * invz) + s_pps[2 * cam + 1];

    out[i] = make_float2(ux - p2d.x, uy - p2d.y);
}

// --------------------------------------------------------------- launcher ---
extern "C" void kernel_launch(void* const* d_in, const int* in_sizes, int n_in,
                              void* d_out, int out_size, void* d_ws, size_t ws_size,
                              hipStream_t stream) {
    const float2* points_2d       = (const float2*)d_in[0];
    const int*    camera_indices  = (const int*)d_in[1];
    const int2*   grouping        = (const int2*)d_in[2];
    const int*    point_indices   = (const int*)d_in[3];
    const float*  camera_pps      = (const float*)d_in[4];
    const float*  intrs           = (const float*)d_in[5];
    const float*  points_3d       = (const float*)d_in[6];
    const float*  ref_poses       = (const float*)d_in[7];
    const float*  rel_poses       = (const float*)d_in[8];
    float2*       out             = (float2*)d_out;

    int n = in_sizes[1];  // N observations (camera_indices is (N,))
    size_t need = (size_t)NGRP * 32;  // 320 KB

    if (d_ws && ws_size >= need) {
        f4* ws = (f4*)d_ws;

        // Co-residency capacity for the cooperative launch (computed once).
        static int coopBlocks = -1;
        if (coopBlocks < 0) {
            int perCU = 0, nCU = 0;
            hipError_t e1 = hipOccupancyMaxActiveBlocksPerMultiprocessor(
                &perCU, (const void*)fused_kernel, 256, 0);
            hipDeviceProp_t prop;
            hipError_t e2 = hipGetDeviceProperties(&prop, 0);
            if (e2 == hipSuccess) nCU = prop.multiProcessorCount;
            coopBlocks = (e1 == hipSuccess && perCU > 0 && nCU > 0)
                             ? perCU * nCU : 0;
        }

        if (coopBlocks > 0) {
            int blocks = coopBlocks;
            int maxUseful = (n + 255) / 256;
            if (blocks > maxUseful) blocks = maxUseful;
            void* args[] = {
                (void*)&points_2d, (void*)&camera_indices, (void*)&grouping,
                (void*)&point_indices, (void*)&camera_pps, (void*)&intrs,
                (void*)&points_3d, (void*)&ref_poses, (void*)&rel_poses,
                (void*)&ws, (void*)&out, (void*)&n };
            hipError_t err = hipLaunchCooperativeKernel(
                (const void*)fused_kernel, dim3(blocks), dim3(256),
                args, 0, stream);
            if (err == hipSuccess) return;
        }

        // Fallback: R4 two-dispatch path
        int blocks = (n + 255) / 256;
        repack_ref_kernel<<<(NGRP + 255) / 256, 256, 0, stream>>>(ref_poses, ws);
        reproj_kernel<<<blocks, 256, 0, stream>>>(
            points_2d, camera_indices, grouping, point_indices,
            camera_pps, intrs, points_3d, ws, rel_poses, out, n);
    } else {
        int blocks = (n + 255) / 256;
        reproj_inline_kernel<<<blocks, 256, 0, stream>>>(
            points_2d, camera_indices, grouping, point_indices,
            camera_pps, intrs, points_3d, ref_poses, rel_poses, out, n);
    }
}

// Round 6
// 129.842 us; speedup vs baseline: 1.8848x; 1.8848x over previous
//
#include <hip/hip_runtime.h>

// Reprojection multi-rig model.
// out[i] = intrs[cam]*(p_cam.xy/p_cam.z) + pps[cam] - points_2d[i]
// where p_cam = R(q)*points_3d[pi] + t,
//       q = rel_q (x) ref_q,  t = rel_t + R(rel_q)*ref_t
// Quaternions stored [x,y,z,w]; rotation p + 2*(w*(v x p) + v x (v x p)).
//
// R6 = R0 champion (single dispatch — every extra dispatch node costs
// ~4-5us of graph gap, eating any body win; cooperative launch is 5x
// poison on gfx950: R5) + ONE change: non-temporal hints on the 48MB
// read-once streams and 16MB write-once output so they don't evict the
// L2-resident gather tables (6MB points_3d + 0.28MB ref_poses).
// FP order byte-identical to R0.
//
// Per-elem line-touch ledger (validated R0-R4): streams 0.5 + pose 2.31
// + point 1.125 + store 0.125 ~= 4.3 units ~= 44-45us. Proven non-levers:
// per-wave MLP (R2), VALU removal (R3), bigger ws footprint (R3),
// repack dispatch (R4 net), cooperative fuse (R5).

typedef float f2v __attribute__((ext_vector_type(2)));
typedef int   i2v __attribute__((ext_vector_type(2)));

__global__ __launch_bounds__(256) void reproj_kernel(
    const float2* __restrict__ points_2d,
    const int*    __restrict__ camera_indices,
    const int2*   __restrict__ grouping_indices,
    const int*    __restrict__ point_indices,
    const float*  __restrict__ camera_pps,
    const float*  __restrict__ intrs,
    const float*  __restrict__ points_3d,
    const float*  __restrict__ ref_poses,
    const float*  __restrict__ rel_poses,
    float2*       __restrict__ out,
    int n)
{
    // Tiny read-only tables -> LDS (broadcast reads)
    __shared__ float s_rel[56];   // 8 rel poses x 7
    __shared__ float s_pps[16];   // 8 cams x 2
    __shared__ float s_intr[16];  // 8 cams x 2
    int tid = threadIdx.x;
    if (tid < 56) s_rel[tid] = rel_poses[tid];
    if (tid < 16) { s_pps[tid] = camera_pps[tid]; s_intr[tid] = intrs[tid]; }
    __syncthreads();

    int i = blockIdx.x * blockDim.x + tid;
    if (i >= n) return;

    // Coalesced read-once streams: non-temporal (don't evict gather tables)
    i2v gmv = __builtin_nontemporal_load((const i2v*)grouping_indices + i);
    int pi  = __builtin_nontemporal_load(point_indices + i);
    int cam = __builtin_nontemporal_load(camera_indices + i);
    f2v p2v = __builtin_nontemporal_load((const f2v*)points_2d + i);
    int gx = gmv.x, gy = gmv.y;
    float p2x = p2v.x, p2y = p2v.y;

    // ref pose gather (280 KB table, L2-resident)
    const float* rp = ref_poses + 7 * gx;
    float rtx = rp[0], rty = rp[1], rtz = rp[2];
    float rqx = rp[3], rqy = rp[4], rqz = rp[5], rqw = rp[6];

    // rel pose from LDS
    const float* lp = s_rel + 7 * gy;
    float ltx = lp[0], lty = lp[1], ltz = lp[2];
    float lqx = lp[3], lqy = lp[4], lqz = lp[5], lqw = lp[6];

    // t = rel_t + quat_rotate(rel_q, ref_t)
    float uvx = lqy * rtz - lqz * rty;
    float uvy = lqz * rtx - lqx * rtz;
    float uvz = lqx * rty - lqy * rtx;
    float uuvx = lqy * uvz - lqz * uvy;
    float uuvy = lqz * uvx - lqx * uvz;
    float uuvz = lqx * uvy - lqy * uvx;
    float tx = ltx + rtx + 2.0f * (lqw * uvx + uuvx);
    float ty = lty + rty + 2.0f * (lqw * uvy + uuvy);
    float tz = ltz + rtz + 2.0f * (lqw * uvz + uuvz);

    // q = quat_mul(rel_q, ref_q): w = w1*w2 - dot(v1,v2); v = w1*v2 + w2*v1 + v1 x v2
    float qw = lqw * rqw - (lqx * rqx + lqy * rqy + lqz * rqz);
    float qx = lqw * rqx + rqw * lqx + (lqy * rqz - lqz * rqy);
    float qy = lqw * rqy + rqw * lqy + (lqz * rqx - lqx * rqz);
    float qz = lqw * rqz + rqw * lqz + (lqx * rqy - lqy * rqx);

    // 3D point gather (6 MB table, L2-resident when not evicted)
    const float* pp = points_3d + 3 * pi;
    float px = pp[0], py = pp[1], pz = pp[2];

    // p_cam = quat_rotate(q, p) + t
    float v2x = qy * pz - qz * py;
    float v2y = qz * px - qx * pz;
    float v2z = qx * py - qy * px;
    float w2x = qy * v2z - qz * v2y;
    float w2y = qz * v2x - qx * v2z;
    float w2z = qx * v2y - qy * v2x;
    float pcx = px + 2.0f * (qw * v2x + w2x) + tx;
    float pcy = py + 2.0f * (qw * v2y + w2y) + ty;
    float pcz = pz + 2.0f * (qw * v2z + w2z) + tz;

    float invz = 1.0f / pcz;  // IEEE divide for numpy-matching accuracy
    float ux = s_intr[2 * cam]     * (pcx * invz) + s_pps[2 * cam];
    float uy = s_intr[2 * cam + 1] * (pcy * invz) + s_pps[2 * cam + 1];

    // Write-once output: non-temporal (no L2 allocation)
    f2v o; o.x = ux - p2x; o.y = uy - p2y;
    __builtin_nontemporal_store(o, (f2v*)out + i);
}

extern "C" void kernel_launch(void* const* d_in, const int* in_sizes, int n_in,
                              void* d_out, int out_size, void* d_ws, size_t ws_size,
                              hipStream_t stream) {
    const float2* points_2d       = (const float2*)d_in[0];
    const int*    camera_indices  = (const int*)d_in[1];
    const int2*   grouping        = (const int2*)d_in[2];
    const int*    point_indices   = (const int*)d_in[3];
    const float*  camera_pps      = (const float*)d_in[4];
    const float*  intrs           = (const float*)d_in[5];
    const float*  points_3d       = (const float*)d_in[6];
    const float*  ref_poses       = (const float*)d_in[7];
    const float*  rel_poses       = (const float*)d_in[8];
    float2*       out             = (float2*)d_out;

    int n = in_sizes[1];  // N observations (camera_indices is (N,))
    int blocks = (n + 255) / 256;
    reproj_kernel<<<blocks, 256, 0, stream>>>(
        points_2d, camera_indices, grouping, point_indices,
        camera_pps, intrs, points_3d, ref_poses, rel_poses, out, n);
}